// Round 7
// baseline (500.810 us; speedup 1.0000x reference)
//
#include <hip/hip_runtime.h>

#define NNODE 500000
#define NEDGE 8000000

#define LOCALN 512                    // nodes per bucket (power of 2)
#define NBUCKET 977                   // ceil(500000 / 512)
#define EPB 65536                     // edges per scatter block (footprint fix)
#define NBLK 123                      // ceil(NEDGE / EPB)
#define M_CNT (NBUCKET * NBLK)        // 120171 count-matrix entries
#define NSCANBLK 118                  // ceil(M_CNT / 1024)
#define MAXB 9216                     // max edges per bucket (mean 8192, sigma 90)

// ---------------------------------------------------------------------------
// Wf[16][32] = W_gcn[16][48] @ W1[48][32]  (one block, 512 threads)
// ---------------------------------------------------------------------------
__global__ void fuse_w_kernel(const float* __restrict__ Wg,
                              const float* __restrict__ W1,
                              float* __restrict__ Wf) {
    int t = threadIdx.x;          // 0..511
    int r = t >> 5;               // 0..15
    int c = t & 31;               // 0..31
    float s = 0.f;
    #pragma unroll
    for (int k = 0; k < 48; ++k) s += Wg[r * 48 + k] * W1[k * 32 + c];
    Wf[t] = s;
}

// ---------------------------------------------------------------------------
// Pass A: per-block bucket histogram (LDS), bucket-major count matrix
// cntT[k*NBLK + b] = #edges of block b with dst in bucket k
// ---------------------------------------------------------------------------
__global__ __launch_bounds__(1024) void hist_kernel(const int* __restrict__ dst,
                                                    int* __restrict__ cntT) {
    __shared__ int h[NBUCKET];
    int t = threadIdx.x, b = blockIdx.x;
    for (int k = t; k < NBUCKET; k += 1024) h[k] = 0;
    __syncthreads();
    int base = b * EPB;
    #pragma unroll 8
    for (int i = 0; i < EPB / 1024; ++i) {
        int e = base + i * 1024 + t;
        if (e < NEDGE) atomicAdd(&h[dst[e] >> 9], 1);
    }
    __syncthreads();
    for (int k = t; k < NBUCKET; k += 1024) cntT[k * NBLK + b] = h[k];
}

// ---------------------------------------------------------------------------
// Exclusive scan of cntT (M_CNT elements, bucket-major): 3-kernel scan
// ---------------------------------------------------------------------------
__global__ __launch_bounds__(1024) void scanA_kernel(int* __restrict__ data,
                                                     int* __restrict__ partial) {
    __shared__ int sd[1024];
    int t = threadIdx.x;
    int i = blockIdx.x * 1024 + t;
    int v = (i < M_CNT) ? data[i] : 0;
    sd[t] = v;
    __syncthreads();
    #pragma unroll
    for (int off = 1; off < 1024; off <<= 1) {
        int x = (t >= off) ? sd[t - off] : 0;
        __syncthreads();
        sd[t] += x;
        __syncthreads();
    }
    if (i < M_CNT) data[i] = sd[t] - v;            // exclusive
    if (t == 1023) partial[blockIdx.x] = sd[1023]; // block total
}

__global__ __launch_bounds__(512) void scan2_kernel(int* __restrict__ partial) {
    __shared__ int sd[512];
    int t = threadIdx.x;
    int v = (t < NSCANBLK) ? partial[t] : 0;
    sd[t] = v;
    __syncthreads();
    #pragma unroll
    for (int off = 1; off < 512; off <<= 1) {
        int x = (t >= off) ? sd[t - off] : 0;
        __syncthreads();
        sd[t] += x;
        __syncthreads();
    }
    if (t < NSCANBLK) partial[t] = sd[t] - v;      // exclusive
}

__global__ __launch_bounds__(1024) void scan3_kernel(int* __restrict__ data,
                                                     const int* __restrict__ partial) {
    int i = blockIdx.x * 1024 + threadIdx.x;
    if (i < M_CNT) data[i] += partial[blockIdx.x];
}

// ---------------------------------------------------------------------------
// Pass B: bucket scatter. Each block owns pre-reserved contiguous output
// ranges (from scanned cntT). With NBLK=123, concurrently-open payload
// lines are ~0.9 MB/XCD (<< 4 MiB L2) -> runs stay resident until full,
// write amplification ~1x. No global atomics.
// payload = (src << 9) | (dst & 511)
// ---------------------------------------------------------------------------
__global__ __launch_bounds__(1024) void scatter_kernel(const int* __restrict__ src,
                                                       const int* __restrict__ dst,
                                                       const int* __restrict__ cntT,
                                                       int* __restrict__ payload) {
    __shared__ int cur[NBUCKET];
    int t = threadIdx.x, b = blockIdx.x;
    for (int k = t; k < NBUCKET; k += 1024) cur[k] = cntT[k * NBLK + b];
    __syncthreads();
    int base = b * EPB;
    #pragma unroll 8
    for (int i = 0; i < EPB / 1024; ++i) {
        int e = base + i * 1024 + t;
        if (e < NEDGE) {
            int s = src[e];
            int d = dst[e];
            int r = atomicAdd(&cur[d >> 9], 1);        // LDS atomic (fast, int)
            payload[r] = (s << 9) | (d & 511);
        }
    }
}

// ---------------------------------------------------------------------------
// Pass D: per-bucket degree -> dinv, and per-node degree -> deg16 (uint16)
// so gather_kernel can skip its histogram pass over payload.
// ---------------------------------------------------------------------------
__global__ __launch_bounds__(512) void dinv_kernel(const int* __restrict__ payload,
                                                   const int* __restrict__ cntT,
                                                   float* __restrict__ dinv,
                                                   unsigned short* __restrict__ deg16) {
    __shared__ int h[LOCALN];
    int t = threadIdx.x, k = blockIdx.x;
    h[t] = 0;
    __syncthreads();
    int base = cntT[k * NBLK];
    int end  = (k < NBUCKET - 1) ? cntT[(k + 1) * NBLK] : NEDGE;
    for (int e = base + t; e < end; e += 512) atomicAdd(&h[payload[e] & 511], 1);
    __syncthreads();
    int node = k * LOCALN + t;
    deg16[k * LOCALN + t] = (unsigned short)h[t];
    if (node < NNODE) dinv[node] = rsqrtf((float)(h[t] + 1));   // +1 self-loop
}

// ---------------------------------------------------------------------------
// Pass C: per-bucket LDS counting sort (degrees precomputed) + register
// pull-gather + fused MLP. 1024 threads = 64 groups x 16 lanes.
// ---------------------------------------------------------------------------
__global__ __launch_bounds__(1024) void gather_kernel(
        const float* __restrict__ xx, const int* __restrict__ payload,
        const int* __restrict__ cntT, const float* __restrict__ dinv,
        const unsigned short* __restrict__ deg16,
        const float* __restrict__ Wf, const float* __restrict__ b1,
        const float* __restrict__ W2, const float* __restrict__ b2,
        float* __restrict__ out) {
    __shared__ int   srt[MAXB];
    __shared__ int   nb[LOCALN + 1];
    __shared__ int   cur[LOCALN];
    __shared__ float sWf[512];
    __shared__ float sW2[512];
    __shared__ float sb1[32];
    __shared__ float sb2[16];

    int t = threadIdx.x, k = blockIdx.x;
    if (t < 512) { sWf[t] = Wf[t]; sW2[t] = W2[t]; }
    if (t < 32) sb1[t] = b1[t];
    if (t < 16) sb2[t] = b2[t];
    if (t == 0) nb[0] = 0;
    if (t < LOCALN) nb[t + 1] = deg16[k * LOCALN + t];   // precomputed degrees
    __syncthreads();

    // inclusive scan over nb[1..512] -> nb[i] = local row start of node i
    #pragma unroll
    for (int off = 1; off < 512; off <<= 1) {
        int x = 0;
        if (t < 512 && t >= off) x = nb[t + 1 - off];
        __syncthreads();
        if (t < 512) nb[t + 1] += x;
        __syncthreads();
    }
    if (t < LOCALN) cur[t] = nb[t];
    __syncthreads();

    int base = cntT[k * NBLK];
    int end  = (k < NBUCKET - 1) ? cntT[(k + 1) * NBLK] : NEDGE;
    int n = end - base;

    // placement pass: sort src indices by local dst
    for (int e = t; e < n; e += 1024) {
        int p = payload[base + e];
        int r = atomicAdd(&cur[p & 511], 1);
        srt[r] = p >> 9;
    }
    __syncthreads();

    int g = t >> 4;                 // group 0..63
    int c = t & 15;                 // channel

    #pragma unroll 1
    for (int q = 0; q < LOCALN / 64; ++q) {
        int local = q * 64 + g;     // wave's 4 groups -> 4 consecutive nodes
        int node = k * LOCALN + local;
        if (node < NNODE) {
            float di = dinv[node];
            float xv = xx[(size_t)node * 16 + c];
            float acc = xv * di;    // self-loop term

            int j = nb[local], jend = nb[local + 1];
            for (; j + 4 <= jend; j += 4) {
                int s0 = srt[j], s1 = srt[j + 1], s2 = srt[j + 2], s3 = srt[j + 3];
                float d0 = dinv[s0], d1 = dinv[s1], d2 = dinv[s2], d3 = dinv[s3];
                float v0 = xx[(size_t)s0 * 16 + c];
                float v1 = xx[(size_t)s1 * 16 + c];
                float v2 = xx[(size_t)s2 * 16 + c];
                float v3 = xx[(size_t)s3 * 16 + c];
                acc = fmaf(v0, d0, acc);
                acc = fmaf(v1, d1, acc);
                acc = fmaf(v2, d2, acc);
                acc = fmaf(v3, d3, acc);
            }
            for (; j < jend; ++j) {
                int s = srt[j];
                acc = fmaf(xx[(size_t)s * 16 + c], dinv[s], acc);
            }

            float a = di * acc;

            // hidden layer: lane c computes units c and c+16
            float h0 = sb1[c], h1 = sb1[c + 16];
            #pragma unroll
            for (int kk = 0; kk < 16; ++kk) {
                float av = __shfl(a, kk, 16);
                h0 = fmaf(av, sWf[kk * 32 + c], h0);
                h1 = fmaf(av, sWf[kk * 32 + c + 16], h1);
            }
            h0 = fmaxf(h0, 0.f);
            h1 = fmaxf(h1, 0.f);

            float u = sb2[c];
            #pragma unroll
            for (int jj = 0; jj < 16; ++jj) {
                float hv0 = __shfl(h0, jj, 16);
                float hv1 = __shfl(h1, jj, 16);
                u = fmaf(hv0, sW2[jj * 16 + c], u);
                u = fmaf(hv1, sW2[(jj + 16) * 16 + c], u);
            }

            out[(size_t)node * 16 + c] = xv + u;
        }
    }
}

extern "C" void kernel_launch(void* const* d_in, const int* in_sizes, int n_in,
                              void* d_out, int out_size, void* d_ws, size_t ws_size,
                              hipStream_t stream) {
    const float* xx   = (const float*)d_in[0];
    const int*   edge = (const int*)d_in[1];   // [2, E]: row0 = src, row1 = dst
    const float* Wg   = (const float*)d_in[2];
    const float* W1   = (const float*)d_in[3];
    const float* b1   = (const float*)d_in[4];
    const float* W2   = (const float*)d_in[5];
    const float* b2   = (const float*)d_in[6];
    float* out = (float*)d_out;

    const int* srcI = edge;
    const int* dstI = edge + NEDGE;

    // workspace (4B words):
    // payload[8M] | cntT[120171] | part[512] | dinv[500000] | Wf[512] | deg16[250112w]
    // total = 8,871,307 words <= 9,000,512 available
    int*   ws      = (int*)d_ws;
    int*   payload = ws;
    int*   cntT    = ws + NEDGE;
    int*   part    = ws + NEDGE + M_CNT;
    float* dinv    = (float*)(ws + NEDGE + M_CNT + 512);
    float* Wf      = (float*)(ws + NEDGE + M_CNT + 512 + NNODE);
    unsigned short* deg16 = (unsigned short*)(ws + NEDGE + M_CNT + 512 + NNODE + 512);

    hipLaunchKernelGGL(hist_kernel, dim3(NBLK), dim3(1024), 0, stream, dstI, cntT);

    hipLaunchKernelGGL(scanA_kernel, dim3(NSCANBLK), dim3(1024), 0, stream, cntT, part);
    hipLaunchKernelGGL(scan2_kernel, dim3(1), dim3(512), 0, stream, part);
    hipLaunchKernelGGL(scan3_kernel, dim3(NSCANBLK), dim3(1024), 0, stream, cntT, part);

    hipLaunchKernelGGL(scatter_kernel, dim3(NBLK), dim3(1024), 0, stream,
                       srcI, dstI, cntT, payload);

    hipLaunchKernelGGL(dinv_kernel, dim3(NBUCKET), dim3(512), 0, stream,
                       payload, cntT, dinv, deg16);

    hipLaunchKernelGGL(fuse_w_kernel, dim3(1), dim3(512), 0, stream, Wg, W1, Wf);

    hipLaunchKernelGGL(gather_kernel, dim3(NBUCKET), dim3(1024), 0, stream,
                       xx, payload, cntT, dinv, deg16, Wf, b1, W2, b2, out);
}

// Round 8
// 385.320 us; speedup vs baseline: 1.2997x; 1.2997x over previous
//
#include <hip/hip_runtime.h>

#define NNODE 500000
#define NEDGE 8000000

#define LOCALN 512                    // nodes per bucket (power of 2)
#define NBUCKET 977                   // ceil(500000 / 512)
#define EPB 32768                     // edges per scatter block
#define NBLK 245                      // ceil(NEDGE / EPB)
#define M_CNT (NBUCKET * NBLK)        // 239365 count-matrix entries
#define NSCANBLK 234                  // ceil(M_CNT / 1024)
#define MAXB 9216                     // max edges per bucket (mean 8192, sigma 90)

// scatter dynamic LDS: stage[EPB] | lscan[NBUCKET+1] | gbase[NBUCKET] | lcur[NBUCKET]
#define SCATTER_LDS_WORDS (EPB + (NBUCKET + 1) + NBUCKET + NBUCKET)
#define SCATTER_LDS_BYTES (SCATTER_LDS_WORDS * 4)

// ---------------------------------------------------------------------------
// Wf[16][32] = W_gcn[16][48] @ W1[48][32]  (one block, 512 threads)
// ---------------------------------------------------------------------------
__global__ void fuse_w_kernel(const float* __restrict__ Wg,
                              const float* __restrict__ W1,
                              float* __restrict__ Wf) {
    int t = threadIdx.x;          // 0..511
    int r = t >> 5;               // 0..15
    int c = t & 31;               // 0..31
    float s = 0.f;
    #pragma unroll
    for (int k = 0; k < 48; ++k) s += Wg[r * 48 + k] * W1[k * 32 + c];
    Wf[t] = s;
}

// ---------------------------------------------------------------------------
// Pass A: per-block bucket histogram (LDS), bucket-major count matrix
// cntT[k*NBLK + b] = #edges of block b with dst in bucket k
// ---------------------------------------------------------------------------
__global__ __launch_bounds__(1024) void hist_kernel(const int* __restrict__ dst,
                                                    int* __restrict__ cntT) {
    __shared__ int h[NBUCKET];
    int t = threadIdx.x, b = blockIdx.x;
    for (int k = t; k < NBUCKET; k += 1024) h[k] = 0;
    __syncthreads();
    int base = b * EPB;
    #pragma unroll
    for (int i = 0; i < EPB / 1024; ++i) {
        int e = base + i * 1024 + t;
        if (e < NEDGE) atomicAdd(&h[dst[e] >> 9], 1);
    }
    __syncthreads();
    for (int k = t; k < NBUCKET; k += 1024) cntT[k * NBLK + b] = h[k];
}

// ---------------------------------------------------------------------------
// Exclusive scan of cntT (M_CNT elements, bucket-major): 3-kernel scan
// ---------------------------------------------------------------------------
__global__ __launch_bounds__(1024) void scanA_kernel(int* __restrict__ data,
                                                     int* __restrict__ partial) {
    __shared__ int sd[1024];
    int t = threadIdx.x;
    int i = blockIdx.x * 1024 + t;
    int v = (i < M_CNT) ? data[i] : 0;
    sd[t] = v;
    __syncthreads();
    #pragma unroll
    for (int off = 1; off < 1024; off <<= 1) {
        int x = (t >= off) ? sd[t - off] : 0;
        __syncthreads();
        sd[t] += x;
        __syncthreads();
    }
    if (i < M_CNT) data[i] = sd[t] - v;            // exclusive
    if (t == 1023) partial[blockIdx.x] = sd[1023]; // block total
}

__global__ __launch_bounds__(512) void scan2_kernel(int* __restrict__ partial) {
    __shared__ int sd[512];
    int t = threadIdx.x;
    int v = (t < NSCANBLK) ? partial[t] : 0;
    sd[t] = v;
    __syncthreads();
    #pragma unroll
    for (int off = 1; off < 512; off <<= 1) {
        int x = (t >= off) ? sd[t - off] : 0;
        __syncthreads();
        sd[t] += x;
        __syncthreads();
    }
    if (t < NSCANBLK) partial[t] = sd[t] - v;      // exclusive
}

__global__ __launch_bounds__(1024) void scan3_kernel(int* __restrict__ data,
                                                     const int* __restrict__ partial) {
    int i = blockIdx.x * 1024 + threadIdx.x;
    if (i < M_CNT) data[i] += partial[blockIdx.x];
}

// ---------------------------------------------------------------------------
// Pass B: bucket scatter with LDS staging (full write combining).
// Per block: local counting sort of its 32K edges in LDS (hist -> scan ->
// placement into stage[]), then run-based flush: consecutive lanes write
// consecutive payload addresses -> every 64B line written once, by one wave.
// Payload content identical to the unstaged version.
// payload = (src << 9) | (dst & 511)
// ---------------------------------------------------------------------------
__global__ __launch_bounds__(1024) void scatter_kernel(const int* __restrict__ src,
                                                       const int* __restrict__ dst,
                                                       const int* __restrict__ cntT,
                                                       int* __restrict__ payload) {
    extern __shared__ int smem[];
    int* stage = smem;                       // [EPB]
    int* lscan = smem + EPB;                 // [NBUCKET+1]
    int* gbase = lscan + (NBUCKET + 1);      // [NBUCKET]
    int* lcur  = gbase + NBUCKET;            // [NBUCKET]

    int t = threadIdx.x, b = blockIdx.x;
    int base = b * EPB;

    // phase 1: local histogram (counts at lscan[1..NBUCKET])
    for (int k = t; k <= NBUCKET; k += 1024) lscan[k] = 0;
    __syncthreads();
    #pragma unroll
    for (int i = 0; i < EPB / 1024; ++i) {
        int e = base + i * 1024 + t;
        if (e < NEDGE) atomicAdd(&lscan[1 + (dst[e] >> 9)], 1);
    }
    __syncthreads();

    // phase 2: inclusive scan over lscan[1..NBUCKET] -> lscan[k] = local start
    #pragma unroll
    for (int off = 1; off < NBUCKET; off <<= 1) {
        int x = 0;
        if (t < NBUCKET && t >= off) x = lscan[t + 1 - off];
        __syncthreads();
        if (t < NBUCKET) lscan[t + 1] += x;
        __syncthreads();
    }

    // phase 3: load global bases, init cursors
    for (int k = t; k < NBUCKET; k += 1024) {
        gbase[k] = cntT[k * NBLK + b];
        lcur[k]  = lscan[k];
    }
    __syncthreads();

    // phase 4: placement into LDS stage (dst re-read is L2-hot)
    #pragma unroll
    for (int i = 0; i < EPB / 1024; ++i) {
        int e = base + i * 1024 + t;
        if (e < NEDGE) {
            int s = src[e];
            int d = dst[e];
            int k = d >> 9;
            int r = atomicAdd(&lcur[k], 1);
            stage[r] = (s << 9) | (d & 511);
        }
    }
    __syncthreads();

    // phase 5: run-based flush, one wave per bucket-run (coalesced writes)
    int wid = t >> 6, lane = t & 63;
    for (int k = wid; k < NBUCKET; k += 16) {
        int s0  = lscan[k];
        int len = lscan[k + 1] - s0;
        int gb  = gbase[k];
        for (int off = lane; off < len; off += 64)
            payload[gb + off] = stage[s0 + off];
    }
}

// ---------------------------------------------------------------------------
// Pass D: per-bucket degree -> dinv, and per-node degree -> deg16 (uint16)
// so gather_kernel can skip its histogram pass over payload.
// ---------------------------------------------------------------------------
__global__ __launch_bounds__(512) void dinv_kernel(const int* __restrict__ payload,
                                                   const int* __restrict__ cntT,
                                                   float* __restrict__ dinv,
                                                   unsigned short* __restrict__ deg16) {
    __shared__ int h[LOCALN];
    int t = threadIdx.x, k = blockIdx.x;
    h[t] = 0;
    __syncthreads();
    int base = cntT[k * NBLK];
    int end  = (k < NBUCKET - 1) ? cntT[(k + 1) * NBLK] : NEDGE;
    for (int e = base + t; e < end; e += 512) atomicAdd(&h[payload[e] & 511], 1);
    __syncthreads();
    int node = k * LOCALN + t;
    deg16[k * LOCALN + t] = (unsigned short)h[t];
    if (node < NNODE) dinv[node] = rsqrtf((float)(h[t] + 1));   // +1 self-loop
}

// ---------------------------------------------------------------------------
// Pass C: per-bucket LDS counting sort (degrees precomputed) + register
// pull-gather + fused MLP. 1024 threads = 64 groups x 16 lanes.
// ---------------------------------------------------------------------------
__global__ __launch_bounds__(1024) void gather_kernel(
        const float* __restrict__ xx, const int* __restrict__ payload,
        const int* __restrict__ cntT, const float* __restrict__ dinv,
        const unsigned short* __restrict__ deg16,
        const float* __restrict__ Wf, const float* __restrict__ b1,
        const float* __restrict__ W2, const float* __restrict__ b2,
        float* __restrict__ out) {
    __shared__ int   srt[MAXB];
    __shared__ int   nb[LOCALN + 1];
    __shared__ int   cur[LOCALN];
    __shared__ float sWf[512];
    __shared__ float sW2[512];
    __shared__ float sb1[32];
    __shared__ float sb2[16];

    int t = threadIdx.x, k = blockIdx.x;
    if (t < 512) { sWf[t] = Wf[t]; sW2[t] = W2[t]; }
    if (t < 32) sb1[t] = b1[t];
    if (t < 16) sb2[t] = b2[t];
    if (t == 0) nb[0] = 0;
    if (t < LOCALN) nb[t + 1] = deg16[k * LOCALN + t];   // precomputed degrees
    __syncthreads();

    // inclusive scan over nb[1..512] -> nb[i] = local row start of node i
    #pragma unroll
    for (int off = 1; off < 512; off <<= 1) {
        int x = 0;
        if (t < 512 && t >= off) x = nb[t + 1 - off];
        __syncthreads();
        if (t < 512) nb[t + 1] += x;
        __syncthreads();
    }
    if (t < LOCALN) cur[t] = nb[t];
    __syncthreads();

    int base = cntT[k * NBLK];
    int end  = (k < NBUCKET - 1) ? cntT[(k + 1) * NBLK] : NEDGE;
    int n = end - base;

    // placement pass: sort src indices by local dst
    for (int e = t; e < n; e += 1024) {
        int p = payload[base + e];
        int r = atomicAdd(&cur[p & 511], 1);
        srt[r] = p >> 9;
    }
    __syncthreads();

    int g = t >> 4;                 // group 0..63
    int c = t & 15;                 // channel

    #pragma unroll 1
    for (int q = 0; q < LOCALN / 64; ++q) {
        int local = q * 64 + g;     // wave's 4 groups -> 4 consecutive nodes
        int node = k * LOCALN + local;
        if (node < NNODE) {
            float di = dinv[node];
            float xv = xx[(size_t)node * 16 + c];
            float acc = xv * di;    // self-loop term

            int j = nb[local], jend = nb[local + 1];
            for (; j + 4 <= jend; j += 4) {
                int s0 = srt[j], s1 = srt[j + 1], s2 = srt[j + 2], s3 = srt[j + 3];
                float d0 = dinv[s0], d1 = dinv[s1], d2 = dinv[s2], d3 = dinv[s3];
                float v0 = xx[(size_t)s0 * 16 + c];
                float v1 = xx[(size_t)s1 * 16 + c];
                float v2 = xx[(size_t)s2 * 16 + c];
                float v3 = xx[(size_t)s3 * 16 + c];
                acc = fmaf(v0, d0, acc);
                acc = fmaf(v1, d1, acc);
                acc = fmaf(v2, d2, acc);
                acc = fmaf(v3, d3, acc);
            }
            for (; j < jend; ++j) {
                int s = srt[j];
                acc = fmaf(xx[(size_t)s * 16 + c], dinv[s], acc);
            }

            float a = di * acc;

            // hidden layer: lane c computes units c and c+16
            float h0 = sb1[c], h1 = sb1[c + 16];
            #pragma unroll
            for (int kk = 0; kk < 16; ++kk) {
                float av = __shfl(a, kk, 16);
                h0 = fmaf(av, sWf[kk * 32 + c], h0);
                h1 = fmaf(av, sWf[kk * 32 + c + 16], h1);
            }
            h0 = fmaxf(h0, 0.f);
            h1 = fmaxf(h1, 0.f);

            float u = sb2[c];
            #pragma unroll
            for (int jj = 0; jj < 16; ++jj) {
                float hv0 = __shfl(h0, jj, 16);
                float hv1 = __shfl(h1, jj, 16);
                u = fmaf(hv0, sW2[jj * 16 + c], u);
                u = fmaf(hv1, sW2[(jj + 16) * 16 + c], u);
            }

            out[(size_t)node * 16 + c] = xv + u;
        }
    }
}

extern "C" void kernel_launch(void* const* d_in, const int* in_sizes, int n_in,
                              void* d_out, int out_size, void* d_ws, size_t ws_size,
                              hipStream_t stream) {
    const float* xx   = (const float*)d_in[0];
    const int*   edge = (const int*)d_in[1];   // [2, E]: row0 = src, row1 = dst
    const float* Wg   = (const float*)d_in[2];
    const float* W1   = (const float*)d_in[3];
    const float* b1   = (const float*)d_in[4];
    const float* W2   = (const float*)d_in[5];
    const float* b2   = (const float*)d_in[6];
    float* out = (float*)d_out;

    const int* srcI = edge;
    const int* dstI = edge + NEDGE;

    // workspace (4B words):
    // payload[8M] | cntT[239365] | part[512] | dinv[500000] | Wf[512] | deg16[250112w]
    // total = 8,990,501 words <= 9,000,512 available
    int*   ws      = (int*)d_ws;
    int*   payload = ws;
    int*   cntT    = ws + NEDGE;
    int*   part    = ws + NEDGE + M_CNT;
    float* dinv    = (float*)(ws + NEDGE + M_CNT + 512);
    float* Wf      = (float*)(ws + NEDGE + M_CNT + 512 + NNODE);
    unsigned short* deg16 = (unsigned short*)(ws + NEDGE + M_CNT + 512 + NNODE + 512);

    // allow >64KB dynamic LDS for the staging scatter (one-time attribute set)
    static bool lds_attr_set = false;
    if (!lds_attr_set) {
        hipFuncSetAttribute((const void*)scatter_kernel,
                            hipFuncAttributeMaxDynamicSharedMemorySize,
                            SCATTER_LDS_BYTES);
        lds_attr_set = true;
    }

    hipLaunchKernelGGL(hist_kernel, dim3(NBLK), dim3(1024), 0, stream, dstI, cntT);

    hipLaunchKernelGGL(scanA_kernel, dim3(NSCANBLK), dim3(1024), 0, stream, cntT, part);
    hipLaunchKernelGGL(scan2_kernel, dim3(1), dim3(512), 0, stream, part);
    hipLaunchKernelGGL(scan3_kernel, dim3(NSCANBLK), dim3(1024), 0, stream, cntT, part);

    hipLaunchKernelGGL(scatter_kernel, dim3(NBLK), dim3(1024), SCATTER_LDS_BYTES,
                       stream, srcI, dstI, cntT, payload);

    hipLaunchKernelGGL(dinv_kernel, dim3(NBUCKET), dim3(512), 0, stream,
                       payload, cntT, dinv, deg16);

    hipLaunchKernelGGL(fuse_w_kernel, dim3(1), dim3(512), 0, stream, Wg, W1, Wf);

    hipLaunchKernelGGL(gather_kernel, dim3(NBUCKET), dim3(1024), 0, stream,
                       xx, payload, cntT, dinv, deg16, Wf, b1, W2, b2, out);
}

// Round 9
// 377.949 us; speedup vs baseline: 1.3251x; 1.0195x over previous
//
#include <hip/hip_runtime.h>

#define NNODE 500000
#define NEDGE 8000000

#define LOCALN 512                    // nodes per bucket (power of 2)
#define NBUCKET 977                   // ceil(500000 / 512)
#define EPB 32768                     // edges per scatter block
#define NBLK 245                      // ceil(NEDGE / EPB)
#define M_CNT (NBUCKET * NBLK)        // 239365 count-matrix entries
#define NSCANBLK 234                  // ceil(M_CNT / 1024)
#define MAXB 9216                     // max edges per bucket (mean 8192, sigma 90)

// scatter dynamic LDS: stage[EPB] | lscan[NBUCKET+1] | gbase[NBUCKET] | lcur[NBUCKET]
#define SCATTER_LDS_WORDS (EPB + (NBUCKET + 1) + NBUCKET + NBUCKET)
#define SCATTER_LDS_BYTES (SCATTER_LDS_WORDS * 4)

// ---------------------------------------------------------------------------
// Pass A: per-block bucket histogram (LDS), bucket-major count matrix
// cntT[k*NBLK + b] = #edges of block b with dst in bucket k
// ---------------------------------------------------------------------------
__global__ __launch_bounds__(1024) void hist_kernel(const int* __restrict__ dst,
                                                    int* __restrict__ cntT) {
    __shared__ int h[NBUCKET];
    int t = threadIdx.x, b = blockIdx.x;
    for (int k = t; k < NBUCKET; k += 1024) h[k] = 0;
    __syncthreads();
    int base = b * EPB;
    #pragma unroll
    for (int i = 0; i < EPB / 1024; ++i) {
        int e = base + i * 1024 + t;
        if (e < NEDGE) atomicAdd(&h[dst[e] >> 9], 1);
    }
    __syncthreads();
    for (int k = t; k < NBUCKET; k += 1024) cntT[k * NBLK + b] = h[k];
}

// ---------------------------------------------------------------------------
// Exclusive scan of cntT (M_CNT elements, bucket-major): 3-kernel scan
// ---------------------------------------------------------------------------
__global__ __launch_bounds__(1024) void scanA_kernel(int* __restrict__ data,
                                                     int* __restrict__ partial) {
    __shared__ int sd[1024];
    int t = threadIdx.x;
    int i = blockIdx.x * 1024 + t;
    int v = (i < M_CNT) ? data[i] : 0;
    sd[t] = v;
    __syncthreads();
    #pragma unroll
    for (int off = 1; off < 1024; off <<= 1) {
        int x = (t >= off) ? sd[t - off] : 0;
        __syncthreads();
        sd[t] += x;
        __syncthreads();
    }
    if (i < M_CNT) data[i] = sd[t] - v;            // exclusive
    if (t == 1023) partial[blockIdx.x] = sd[1023]; // block total
}

// scan of the block totals (one block, 512 threads) + fused Wf compute
// Wf[16][32] = W_gcn[16][48] @ W1[48][32]  (threads 0..511, after the scan)
__global__ __launch_bounds__(512) void scan2_kernel(int* __restrict__ partial,
                                                    const float* __restrict__ Wg,
                                                    const float* __restrict__ W1,
                                                    float* __restrict__ Wf) {
    __shared__ int sd[512];
    int t = threadIdx.x;
    int v = (t < NSCANBLK) ? partial[t] : 0;
    sd[t] = v;
    __syncthreads();
    #pragma unroll
    for (int off = 1; off < 512; off <<= 1) {
        int x = (t >= off) ? sd[t - off] : 0;
        __syncthreads();
        sd[t] += x;
        __syncthreads();
    }
    if (t < NSCANBLK) partial[t] = sd[t] - v;      // exclusive

    // fused: Wf (independent of the scan; no barrier needed)
    int r = t >> 5;               // 0..15
    int c = t & 31;               // 0..31
    float s = 0.f;
    #pragma unroll
    for (int k = 0; k < 48; ++k) s += Wg[r * 48 + k] * W1[k * 32 + c];
    Wf[t] = s;
}

__global__ __launch_bounds__(1024) void scan3_kernel(int* __restrict__ data,
                                                     const int* __restrict__ partial) {
    int i = blockIdx.x * 1024 + threadIdx.x;
    if (i < M_CNT) data[i] += partial[blockIdx.x];
}

// ---------------------------------------------------------------------------
// Pass B: bucket scatter with LDS staging (full write combining).
// Local per-bucket counts are DERIVED from the scanned cntT by adjacency
// (h_b[k] = cntT[next] - cntT[idx]) -- no histogram pass, no dst re-read.
// Then: local scan -> atomic placement into stage[] -> run-based flush with
// consecutive lanes writing consecutive payload addresses (write amp ~1x).
// payload = (src << 9) | (dst & 511)
// ---------------------------------------------------------------------------
__global__ __launch_bounds__(1024) void scatter_kernel(const int* __restrict__ src,
                                                       const int* __restrict__ dst,
                                                       const int* __restrict__ cntT,
                                                       int* __restrict__ payload) {
    extern __shared__ int smem[];
    int* stage = smem;                       // [EPB]
    int* lscan = smem + EPB;                 // [NBUCKET+1]
    int* gbase = lscan + (NBUCKET + 1);      // [NBUCKET]
    int* lcur  = gbase + NBUCKET;            // [NBUCKET]

    int t = threadIdx.x, b = blockIdx.x;
    int base = b * EPB;

    // phase 1: derive this block's counts + global bases from scanned cntT
    if (t == 0) lscan[0] = 0;
    for (int k = t; k < NBUCKET; k += 1024) {
        int idx = k * NBLK + b;
        int g0 = cntT[idx];
        int g1 = (idx + 1 < M_CNT) ? cntT[idx + 1] : NEDGE;
        gbase[k] = g0;
        lscan[k + 1] = g1 - g0;              // count h_b[k]
    }
    __syncthreads();

    // phase 2: inclusive scan over lscan[1..NBUCKET] -> lscan[k] = local start
    #pragma unroll
    for (int off = 1; off < NBUCKET; off <<= 1) {
        int x = 0;
        if (t < NBUCKET && t >= off) x = lscan[t + 1 - off];
        __syncthreads();
        if (t < NBUCKET) lscan[t + 1] += x;
        __syncthreads();
    }
    for (int k = t; k < NBUCKET; k += 1024) lcur[k] = lscan[k];
    __syncthreads();

    // phase 3: placement into LDS stage
    #pragma unroll
    for (int i = 0; i < EPB / 1024; ++i) {
        int e = base + i * 1024 + t;
        if (e < NEDGE) {
            int s = src[e];
            int d = dst[e];
            int k = d >> 9;
            int r = atomicAdd(&lcur[k], 1);
            stage[r] = (s << 9) | (d & 511);
        }
    }
    __syncthreads();

    // phase 4: run-based flush, one wave per bucket-run (coalesced writes)
    int wid = t >> 6, lane = t & 63;
    for (int k = wid; k < NBUCKET; k += 16) {
        int s0  = lscan[k];
        int len = lscan[k + 1] - s0;
        int gb  = gbase[k];
        for (int off = lane; off < len; off += 64)
            payload[gb + off] = stage[s0 + off];
    }
}

// ---------------------------------------------------------------------------
// Pass D: per-bucket degree -> dinv, and per-node degree -> deg16 (uint16)
// so gather_kernel can skip its histogram pass over payload.
// ---------------------------------------------------------------------------
__global__ __launch_bounds__(512) void dinv_kernel(const int* __restrict__ payload,
                                                   const int* __restrict__ cntT,
                                                   float* __restrict__ dinv,
                                                   unsigned short* __restrict__ deg16) {
    __shared__ int h[LOCALN];
    int t = threadIdx.x, k = blockIdx.x;
    h[t] = 0;
    __syncthreads();
    int base = cntT[k * NBLK];
    int end  = (k < NBUCKET - 1) ? cntT[(k + 1) * NBLK] : NEDGE;
    for (int e = base + t; e < end; e += 512) atomicAdd(&h[payload[e] & 511], 1);
    __syncthreads();
    int node = k * LOCALN + t;
    deg16[k * LOCALN + t] = (unsigned short)h[t];
    if (node < NNODE) dinv[node] = rsqrtf((float)(h[t] + 1));   // +1 self-loop
}

// ---------------------------------------------------------------------------
// Pass C: per-bucket LDS counting sort (degrees precomputed) + register
// pull-gather + fused MLP. 1024 threads = 64 groups x 16 lanes.
// ---------------------------------------------------------------------------
__global__ __launch_bounds__(1024) void gather_kernel(
        const float* __restrict__ xx, const int* __restrict__ payload,
        const int* __restrict__ cntT, const float* __restrict__ dinv,
        const unsigned short* __restrict__ deg16,
        const float* __restrict__ Wf, const float* __restrict__ b1,
        const float* __restrict__ W2, const float* __restrict__ b2,
        float* __restrict__ out) {
    __shared__ int   srt[MAXB];
    __shared__ int   nb[LOCALN + 1];
    __shared__ int   cur[LOCALN];
    __shared__ float sWf[512];
    __shared__ float sW2[512];
    __shared__ float sb1[32];
    __shared__ float sb2[16];

    int t = threadIdx.x, k = blockIdx.x;
    if (t < 512) { sWf[t] = Wf[t]; sW2[t] = W2[t]; }
    if (t < 32) sb1[t] = b1[t];
    if (t < 16) sb2[t] = b2[t];
    if (t == 0) nb[0] = 0;
    if (t < LOCALN) nb[t + 1] = deg16[k * LOCALN + t];   // precomputed degrees
    __syncthreads();

    // inclusive scan over nb[1..512] -> nb[i] = local row start of node i
    #pragma unroll
    for (int off = 1; off < 512; off <<= 1) {
        int x = 0;
        if (t < 512 && t >= off) x = nb[t + 1 - off];
        __syncthreads();
        if (t < 512) nb[t + 1] += x;
        __syncthreads();
    }
    if (t < LOCALN) cur[t] = nb[t];
    __syncthreads();

    int base = cntT[k * NBLK];
    int end  = (k < NBUCKET - 1) ? cntT[(k + 1) * NBLK] : NEDGE;
    int n = end - base;

    // placement pass: sort src indices by local dst
    for (int e = t; e < n; e += 1024) {
        int p = payload[base + e];
        int r = atomicAdd(&cur[p & 511], 1);
        srt[r] = p >> 9;
    }
    __syncthreads();

    int g = t >> 4;                 // group 0..63
    int c = t & 15;                 // channel

    #pragma unroll 1
    for (int q = 0; q < LOCALN / 64; ++q) {
        int local = q * 64 + g;     // wave's 4 groups -> 4 consecutive nodes
        int node = k * LOCALN + local;
        if (node < NNODE) {
            float di = dinv[node];
            float xv = xx[(size_t)node * 16 + c];
            float acc = xv * di;    // self-loop term

            int j = nb[local], jend = nb[local + 1];
            for (; j + 4 <= jend; j += 4) {
                int s0 = srt[j], s1 = srt[j + 1], s2 = srt[j + 2], s3 = srt[j + 3];
                float d0 = dinv[s0], d1 = dinv[s1], d2 = dinv[s2], d3 = dinv[s3];
                float v0 = xx[(size_t)s0 * 16 + c];
                float v1 = xx[(size_t)s1 * 16 + c];
                float v2 = xx[(size_t)s2 * 16 + c];
                float v3 = xx[(size_t)s3 * 16 + c];
                acc = fmaf(v0, d0, acc);
                acc = fmaf(v1, d1, acc);
                acc = fmaf(v2, d2, acc);
                acc = fmaf(v3, d3, acc);
            }
            for (; j < jend; ++j) {
                int s = srt[j];
                acc = fmaf(xx[(size_t)s * 16 + c], dinv[s], acc);
            }

            float a = di * acc;

            // hidden layer: lane c computes units c and c+16
            float h0 = sb1[c], h1 = sb1[c + 16];
            #pragma unroll
            for (int kk = 0; kk < 16; ++kk) {
                float av = __shfl(a, kk, 16);
                h0 = fmaf(av, sWf[kk * 32 + c], h0);
                h1 = fmaf(av, sWf[kk * 32 + c + 16], h1);
            }
            h0 = fmaxf(h0, 0.f);
            h1 = fmaxf(h1, 0.f);

            float u = sb2[c];
            #pragma unroll
            for (int jj = 0; jj < 16; ++jj) {
                float hv0 = __shfl(h0, jj, 16);
                float hv1 = __shfl(h1, jj, 16);
                u = fmaf(hv0, sW2[jj * 16 + c], u);
                u = fmaf(hv1, sW2[(jj + 16) * 16 + c], u);
            }

            out[(size_t)node * 16 + c] = xv + u;
        }
    }
}

extern "C" void kernel_launch(void* const* d_in, const int* in_sizes, int n_in,
                              void* d_out, int out_size, void* d_ws, size_t ws_size,
                              hipStream_t stream) {
    const float* xx   = (const float*)d_in[0];
    const int*   edge = (const int*)d_in[1];   // [2, E]: row0 = src, row1 = dst
    const float* Wg   = (const float*)d_in[2];
    const float* W1   = (const float*)d_in[3];
    const float* b1   = (const float*)d_in[4];
    const float* W2   = (const float*)d_in[5];
    const float* b2   = (const float*)d_in[6];
    float* out = (float*)d_out;

    const int* srcI = edge;
    const int* dstI = edge + NEDGE;

    // workspace (4B words):
    // payload[8M] | cntT[239365] | part[512] | dinv[500000] | Wf[512] | deg16[250112w]
    // total = 8,990,501 words <= 9,000,512 available
    int*   ws      = (int*)d_ws;
    int*   payload = ws;
    int*   cntT    = ws + NEDGE;
    int*   part    = ws + NEDGE + M_CNT;
    float* dinv    = (float*)(ws + NEDGE + M_CNT + 512);
    float* Wf      = (float*)(ws + NEDGE + M_CNT + 512 + NNODE);
    unsigned short* deg16 = (unsigned short*)(ws + NEDGE + M_CNT + 512 + NNODE + 512);

    // allow >64KB dynamic LDS for the staging scatter (one-time attribute set)
    static bool lds_attr_set = false;
    if (!lds_attr_set) {
        hipFuncSetAttribute((const void*)scatter_kernel,
                            hipFuncAttributeMaxDynamicSharedMemorySize,
                            SCATTER_LDS_BYTES);
        lds_attr_set = true;
    }

    hipLaunchKernelGGL(hist_kernel, dim3(NBLK), dim3(1024), 0, stream, dstI, cntT);

    hipLaunchKernelGGL(scanA_kernel, dim3(NSCANBLK), dim3(1024), 0, stream, cntT, part);
    hipLaunchKernelGGL(scan2_kernel, dim3(1), dim3(512), 0, stream, part, Wg, W1, Wf);
    hipLaunchKernelGGL(scan3_kernel, dim3(NSCANBLK), dim3(1024), 0, stream, cntT, part);

    hipLaunchKernelGGL(scatter_kernel, dim3(NBLK), dim3(1024), SCATTER_LDS_BYTES,
                       stream, srcI, dstI, cntT, payload);

    hipLaunchKernelGGL(dinv_kernel, dim3(NBUCKET), dim3(512), 0, stream,
                       payload, cntT, dinv, deg16);

    hipLaunchKernelGGL(gather_kernel, dim3(NBUCKET), dim3(1024), 0, stream,
                       xx, payload, cntT, dinv, deg16, Wf, b1, W2, b2, out);
}